// Round 5
// baseline (451.489 us; speedup 1.0000x reference)
//
#include <hip/hip_runtime.h>

#define N_NODES 8192
#define M_EDGES 2048
#define KK      16
#define QKD     256
#define VD      256
#define P_PAIRS 120   // 16*15/2
#define CAP2    32    // max member edges per node (avg 4, binomial tail << 32)
#define NPART   64    // mean-reduction partials
#define FSTRIDE (QKD + 4)
#define GRID_BLKS 1024
#define SCALE   0.17677669529663687f   // (256/8)^-0.5

// ---------------- K0: zero ecounts + barrier state ----------------
// (NOT hipMemsetAsync: rocclr fill path is slow/latency-laden for tiny sizes)
__global__ void zero_prep(int* __restrict__ p, int count) {
    int i = blockIdx.x * blockDim.x + threadIdx.x;
    if (i < count) p[i] = 0;
}

// ---------------- hand-rolled grid barrier (all blocks co-resident) ----------
// bar layout: [idx*2] = arrival count, [idx*2+1] = release flag. Zeroed per call.
__device__ __forceinline__ void grid_barrier(int* bar, int idx) {
    __syncthreads();
    if (threadIdx.x == 0) {
        int* cnt = bar + idx * 2;
        int* flg = bar + idx * 2 + 1;
        __threadfence();  // release this block's writes (device scope)
        int arrived = __hip_atomic_fetch_add(cnt, 1, __ATOMIC_ACQ_REL,
                                             __HIP_MEMORY_SCOPE_AGENT) + 1;
        if (arrived == (int)gridDim.x) {
            __hip_atomic_store(flg, 1, __ATOMIC_RELEASE, __HIP_MEMORY_SCOPE_AGENT);
        } else {
            while (__hip_atomic_load(flg, __ATOMIC_ACQUIRE,
                                     __HIP_MEMORY_SCOPE_AGENT) == 0) {
                __builtin_amdgcn_s_sleep(16);
            }
        }
        __threadfence();  // acquire: invalidate stale cached lines
    }
    __syncthreads();
}

// ---------------- fused persistent kernel: scan | weights | mean | attn -------
// 1024 blocks x 256 threads, __launch_bounds__(256,4) => VGPR<=128, LDS 18KB
// => >=4 blocks/CU capacity => all 1024 blocks co-resident (barrier-safe).
__global__ __launch_bounds__(256, 4) void fused(
        const float4* __restrict__ adj4, const float* __restrict__ x1,
        const float* __restrict__ x2,   const float* __restrict__ v,
        float* __restrict__ out,
        int* __restrict__ ecounts, int* __restrict__ ncounts,
        int* __restrict__ enodes,  int* __restrict__ nedges,
        float* __restrict__ w,     float* __restrict__ partials,
        int* __restrict__ bar) {
    __shared__ float f[KK][FSTRIDE];     // ~16.6 KB
    __shared__ int   ids[KK];
    __shared__ float part[P_PAIRS][2];
    __shared__ float d2s[P_PAIRS];
    __shared__ float sigma2;
    __shared__ float esum[4];

    const int t      = threadIdx.x;
    const int gtid   = blockIdx.x * blockDim.x + t;
    const int nthr   = gridDim.x * blockDim.x;
    const int gwave  = gtid >> 6;
    const int nwaves = nthr >> 6;
    const int lane   = t & 63;

    // ---- P1: wave-per-row ballot scan of adj (coalesced float4, 67 MB once)
    {
        const unsigned long long below = (1ull << lane) - 1ull;
        for (int n = gwave; n < N_NODES; n += nwaves) {
            const float4* row = adj4 + n * (M_EDGES / 4);
            int base = 0;
            #pragma unroll
            for (int c = 0; c < M_EDGES / 4 / 64; ++c) {   // 8 chunks
                float4 a = row[c * 64 + lane];
                unsigned long long b0 = __ballot(a.x > 0.f);
                unsigned long long b1 = __ballot(a.y > 0.f);
                unsigned long long b2 = __ballot(a.z > 0.f);
                unsigned long long b3 = __ballot(a.w > 0.f);
                if ((b0 | b1 | b2 | b3) != 0ull) {
                    int pre = __popcll(b0 & below) + __popcll(b1 & below)
                            + __popcll(b2 & below) + __popcll(b3 & below);
                    int mbase = (c * 64 + lane) * 4;
                    float vals[4] = {a.x, a.y, a.z, a.w};
                    int own = 0;
                    #pragma unroll
                    for (int j = 0; j < 4; ++j) {
                        if (vals[j] > 0.f) {
                            int m = mbase + j;
                            int pos = base + pre + own;          // ascending-m
                            if (pos < CAP2) nedges[n * CAP2 + pos] = m;
                            int slot = atomicAdd(&ecounts[m], 1);
                            if (slot < KK) enodes[m * KK + slot] = n;
                            ++own;
                        }
                    }
                }
                base += __popcll(b0) + __popcll(b1) + __popcll(b2) + __popcll(b3);
            }
            if (lane == 0) ncounts[n] = base;
        }
    }
    grid_barrier(bar, 0);

    // ---- P2: per-edge weight w[m] (block per edge, grid-stride)
    for (int m = blockIdx.x; m < M_EDGES; m += gridDim.x) {
        __syncthreads();   // protect f/ids reuse across iterations
        if (t < KK) ids[t] = enodes[m * KK + t];
        __syncthreads();
        if (t == 0) {      // sort -> deterministic order despite atomic scatter
            for (int a = 1; a < KK; ++a) {
                int x = ids[a]; int b = a - 1;
                while (b >= 0 && ids[b] > x) { ids[b + 1] = ids[b]; --b; }
                ids[b + 1] = x;
            }
        }
        __syncthreads();
        for (int k = 0; k < KK; ++k) f[k][t] = x1[ids[k] * QKD + t];
        __syncthreads();

        if (t < 2 * P_PAIRS) {          // pair split across 2 threads
            int p = t >> 1, hh = t & 1;
            int i = 0, pp = p;
            while (pp >= KK - 1 - i) { pp -= KK - 1 - i; ++i; }
            int j = i + 1 + pp;
            const float4* fi = (const float4*)&f[i][0];
            const float4* fj = (const float4*)&f[j][0];
            int base4 = hh << 5;
            float acc = 0.0f;
            #pragma unroll 4
            for (int dd = 0; dd < 32; ++dd) {
                int d4 = base4 + ((dd + t) & 31);
                float4 a = fi[d4], b = fj[d4];
                float dx = a.x - b.x, dy = a.y - b.y, dz = a.z - b.z, dw = a.w - b.w;
                acc += dx * dx + dy * dy + dz * dz + dw * dw;
            }
            part[p][hh] = acc;
        }
        __syncthreads();
        if (t < P_PAIRS) d2s[t] = part[t][0] + part[t][1];
        __syncthreads();

        if (t < P_PAIRS) {   // lower-median rank select (rank 59 of 120)
            float mine = d2s[t];
            int rank = 0;
            for (int q = 0; q < P_PAIRS; ++q) {
                float o = d2s[q];
                rank += (o < mine || (o == mine && q < t)) ? 1 : 0;
            }
            if (rank == (P_PAIRS - 1) / 2) sigma2 = mine * mine;
        }
        __syncthreads();

        float e = (t < P_PAIRS) ? expf(-d2s[t] / sigma2) : 0.0f;
        e += __shfl_xor(e, 32); e += __shfl_xor(e, 16); e += __shfl_xor(e, 8);
        e += __shfl_xor(e, 4);  e += __shfl_xor(e, 2);  e += __shfl_xor(e, 1);
        if ((t & 63) == 0) esum[t >> 6] = e;
        __syncthreads();
        if (t == 0) w[m] = (esum[0] + esum[1] + esum[2] + esum[3]) / (float)(KK * (KK - 1));
    }
    grid_barrier(bar, 1);

    // ---- P3: deterministic partial sums of w[m]*v[m]
    for (int b = blockIdx.x; b < NPART; b += gridDim.x) {
        float acc = 0.0f;
        #pragma unroll 4
        for (int mm = 0; mm < M_EDGES / NPART; ++mm) {
            int m = b * (M_EDGES / NPART) + mm;
            acc += w[m] * v[m * VD + t];
        }
        partials[b * VD + t] = acc;
    }
    grid_barrier(bar, 2);

    // ---- P4: attention, wave-per-node, shuffle-only, online softmax.
    // lane l owns dims {l, l+64, l+128, l+192}; 32-lane-group reduce gives the
    // per-head scores (head of dim d = d>>5); no LDS, no block barriers.
    for (int n = gwave; n < N_NODES; n += nwaves) {
        int C = ncounts[n]; if (C > CAP2) C = CAP2;
        const int* ned = nedges + n * CAP2;
        const float* xq = x1 + n * QKD;
        float q0 = xq[lane]       * SCALE;
        float q1 = xq[lane + 64]  * SCALE;
        float q2 = xq[lane + 128] * SCALE;
        float q3 = xq[lane + 192] * SCALE;
        float mk0 = -INFINITY, mk1 = -INFINITY, mk2 = -INFINITY, mk3 = -INFINITY;
        float l0 = 0, l1 = 0, l2 = 0, l3 = 0;
        float a0 = 0, a1 = 0, a2 = 0, a3 = 0;
        for (int c = 0; c < C; ++c) {
            int m = ned[c];
            float wm = w[m];
            const float* xr = x2 + m * QKD;
            const float* vr = v  + m * VD;
            float p0 = q0 * xr[lane],       p1 = q1 * xr[lane + 64];
            float p2 = q2 * xr[lane + 128], p3 = q3 * xr[lane + 192];
            #pragma unroll
            for (int s = 1; s < 32; s <<= 1) {
                p0 += __shfl_xor(p0, s); p1 += __shfl_xor(p1, s);
                p2 += __shfl_xor(p2, s); p3 += __shfl_xor(p3, s);
            }
            float v0 = vr[lane], v1 = vr[lane + 64], v2 = vr[lane + 128], v3 = vr[lane + 192];
            float nm, fac, e;
            nm = fmaxf(mk0, p0); fac = expf(mk0 - nm); e = expf(p0 - nm);
            l0 = l0 * fac + e; a0 = a0 * fac + e * wm * v0; mk0 = nm;
            nm = fmaxf(mk1, p1); fac = expf(mk1 - nm); e = expf(p1 - nm);
            l1 = l1 * fac + e; a1 = a1 * fac + e * wm * v1; mk1 = nm;
            nm = fmaxf(mk2, p2); fac = expf(mk2 - nm); e = expf(p2 - nm);
            l2 = l2 * fac + e; a2 = a2 * fac + e * wm * v2; mk2 = nm;
            nm = fmaxf(mk3, p3); fac = expf(mk3 - nm); e = expf(p3 - nm);
            l3 = l3 * fac + e; a3 = a3 * fac + e * wm * v3; mk3 = nm;
        }
        float o0, o1, o2, o3;
        if (C > 0) {
            o0 = a0 / l0; o1 = a1 / l1; o2 = a2 / l2; o3 = a3 / l3;
        } else {
            // empty row: softmax over all-NEG is uniform -> mean of w*v
            float s0 = 0, s1 = 0, s2 = 0, s3 = 0;
            #pragma unroll 8
            for (int b = 0; b < NPART; ++b) {
                const float* pp = partials + b * VD;
                s0 += pp[lane];       s1 += pp[lane + 64];
                s2 += pp[lane + 128]; s3 += pp[lane + 192];
            }
            const float inv = 1.0f / (float)M_EDGES;
            o0 = s0 * inv; o1 = s1 * inv; o2 = s2 * inv; o3 = s3 * inv;
        }
        float* op = out + n * VD;
        op[lane] = o0; op[lane + 64] = o1; op[lane + 128] = o2; op[lane + 192] = o3;
    }
}

extern "C" void kernel_launch(void* const* d_in, const int* in_sizes, int n_in,
                              void* d_out, int out_size, void* d_ws, size_t ws_size,
                              hipStream_t stream) {
    const float* x1  = (const float*)d_in[0];   // (N, 256)
    const float* x2  = (const float*)d_in[1];   // (M, 256)
    const float* v   = (const float*)d_in[2];   // (M, 256)
    const float* adj = (const float*)d_in[3];   // (N, M)
    float* out = (float*)d_out;                 // (N, 256)

    // workspace layout (all 4-byte elems), ~1.3 MB total
    float* w        = (float*)d_ws;                 // M
    float* partials = w + M_EDGES;                  // NPART*VD
    int*   ncounts  = (int*)(partials + NPART * VD);// N
    int*   enodes   = ncounts + N_NODES;            // M*KK
    int*   nedges   = enodes + M_EDGES * KK;        // N*CAP2
    int*   ecounts  = nedges + N_NODES * CAP2;      // M   } zeroed together
    int*   bar      = ecounts + M_EDGES;            // 6   }

    const int nzero = M_EDGES + 6;
    zero_prep<<<(nzero + 255) / 256, 256, 0, stream>>>(ecounts, nzero);
    fused<<<GRID_BLKS, 256, 0, stream>>>((const float4*)adj, x1, x2, v, out,
                                         ecounts, ncounts, enodes, nedges,
                                         w, partials, bar);
}